// Round 12
// baseline (264.953 us; speedup 1.0000x reference)
//
#include <hip/hip_runtime.h>
#include <math.h>

#define TOK 2309
#define CH 1024
#define NH 16
#define HD 64
#define NREG 5
#define NTOK (TOK - NREG)    // 2304
#define NPADQ 2432           // 19*128 (query/M padding)
#define NPAD2 2432           // 38*64 key padding == NPADQ (covered by GEMM, no memset)
#define NKT 38
#define HTILES 19            // K-tiles per half (attention split-K)
#define NQROW 2368           // 37*64 rows in attention output partials
#define QSCL 0.1803368801f   // 0.125 * log2(e), folded into K8

typedef unsigned short ushort_t;
typedef unsigned char uchar_t;
typedef __attribute__((ext_vector_type(8))) short s8frag;
typedef __attribute__((ext_vector_type(4))) float f4frag;
typedef __attribute__((ext_vector_type(2))) long ll2;

__device__ __forceinline__ unsigned short f2bf(float x){
  union { float f; unsigned u; } v; v.f = x;
  unsigned r = v.u + 0x7FFF + ((v.u >> 16) & 1);
  return (unsigned short)(r >> 16);
}
__device__ __forceinline__ float bf2f(unsigned short u){
  union { unsigned u32; float f; } v; v.u32 = ((unsigned)u) << 16;
  return v.f;
}
__device__ __forceinline__ unsigned pack_bf16(float lo, float hi){
  union { float f; unsigned u; } a, b;
  a.f = lo; b.f = hi;
  return __builtin_amdgcn_perm(b.u + 0x8000u, a.u + 0x8000u, 0x07060302u);
}
__device__ __forceinline__ uchar_t f2fp8(float x){
  return (uchar_t)(__builtin_amdgcn_cvt_pk_fp8_f32(x, x, 0, false) & 0xff);
}
// async global->LDS 16B/lane; lds ptr must be wave-uniform (HW adds lane*16)
__device__ __forceinline__ void cp16(const void* g, void* l){
  __builtin_amdgcn_global_load_lds(
      (const __attribute__((address_space(1))) unsigned int*)g,
      (__attribute__((address_space(3))) unsigned int*)l, 16, 0, 0);
}

// ---------------- X -> bf16 (rows padded to NPADQ with zeros) -----------------------
__global__ __launch_bounds__(256) void split_x_kernel(
    const float* __restrict__ X, ushort_t* __restrict__ Xbf)
{
  int row = blockIdx.x;
  int c4 = threadIdx.x * 4;
  ushort4 h4 = {0,0,0,0};
  if (row < TOK) {
    float4 v = *(const float4*)&X[(size_t)row*CH + c4];
    h4.x = f2bf(v.x); h4.y = f2bf(v.y); h4.z = f2bf(v.z); h4.w = f2bf(v.w);
  }
  *(ushort4*)&Xbf[(size_t)row*CH + c4] = h4;
}

// ---------------- transpose both weights: W(1024 x N) -> WT(N x 1024) bf16 ----------
__global__ __launch_bounds__(256) void pack_w_kernel(
    const float* __restrict__ Wqkv, const float* __restrict__ Wproj,
    ushort_t* __restrict__ WqkvT, ushort_t* __restrict__ WprojT)
{
  __shared__ float T[64][68];
  const int tid = threadIdx.x;
  int bx = blockIdx.x;
  const float* W; ushort_t* WT; int N;
  if (bx < 48) { W = Wqkv; WT = WqkvT; N = 3*CH; }
  else         { W = Wproj; WT = WprojT; N = CH; bx -= 48; }
  const int n0 = bx * 64;
  const int k0 = blockIdx.y * 64;
  const int lr = tid >> 4;
  const int lc = (tid & 15) * 4;
  #pragma unroll
  for (int s = 0; s < 4; s++) {
    float4 v = *(const float4*)&W[(size_t)(k0 + lr + s*16) * N + n0 + lc];
    *(float4*)&T[lr + s*16][lc] = v;
  }
  __syncthreads();
  const int nl = tid >> 2;
  const int kc = (tid & 3) * 16;
  ushort_t* dh = WT + (size_t)(n0 + nl) * CH + k0 + kc;
  #pragma unroll
  for (int g = 0; g < 4; g++) {
    ushort4 oh;
    oh.x = f2bf(T[kc+g*4+0][nl]); oh.y = f2bf(T[kc+g*4+1][nl]);
    oh.z = f2bf(T[kc+g*4+2][nl]); oh.w = f2bf(T[kc+g*4+3][nl]);
    *(ushort4*)&dh[g*4] = oh;
  }
}

// ---------------- ghat/u kernel: u_h = W_q ghat_h (fp32) ----------------------------
__global__ __launch_bounds__(256) void ghat_kernel(
    const float* __restrict__ G, const float* __restrict__ Wqkv,
    float* __restrict__ U)
{
  const int tid = threadIdx.x;
  const int k = blockIdx.x * 16 + (tid >> 4);
  const int h = tid & 15;
  const float* g = G + h*64;           // g_info[0][0] row h
  float n2 = 0.f;
  #pragma unroll
  for (int d = 0; d < 64; d += 4) {
    float4 gv = *(const float4*)&g[d];
    n2 += gv.x*gv.x + gv.y*gv.y + gv.z*gv.z + gv.w*gv.w;
  }
  const float inv = 1.f / sqrtf(n2);
  const float* wr = Wqkv + (size_t)k*(3*CH) + h*64;
  float dot = 0.f;
  #pragma unroll
  for (int d = 0; d < 64; d += 4) {
    float4 wv = *(const float4*)&wr[d];
    float4 gv = *(const float4*)&g[d];
    dot += wv.x*gv.x + wv.y*gv.y + wv.z*gv.z + wv.w*gv.w;
  }
  U[h*CH + k] = dot * inv;
}

// ---------------- QKV GEMM: uniform 128x128 tile, single-plane bf16 -----------------
// Q -> Qbf bf16 (h,NPADQ,64) + Q8 fp8; K -> K8 fp8 frag-major (scaled by QSCL);
// V -> Vbf bf16 in PV-A-operand layout (k-permuted, as in r11).
__global__ __launch_bounds__(256) void gemm_qkv_mfma(
    const ushort_t* __restrict__ Xbf, const ushort_t* __restrict__ WT,
    ushort_t* __restrict__ Qbf, uchar_t* __restrict__ Q8,
    uchar_t* __restrict__ K8, ushort_t* __restrict__ Vbf)
{
  __shared__ ushort_t LA[2][4096];
  __shared__ ushort_t LB[2][4096];
  const int tid = threadIdx.x;
  const int w = tid >> 6, lane = tid & 63;
  const int quad = lane >> 4, c16 = lane & 15;
  const int wm = w >> 1, wn = w & 1;
  const int nt = blockIdx.x, mt = blockIdx.y;
  const int n0 = nt * 128, m0 = mt * 128;

  const int srow = tid >> 2;
  const int g = (tid & 3) ^ ((tid >> 3) & 3);
  const size_t aoff = (size_t)(m0 + srow)*CH + g*8;
  const size_t boff = (size_t)(n0 + srow)*CH + g*8;
  const int lbase = (tid & 192) * 8;

  f4frag acc[4][4];
  #pragma unroll
  for (int mi = 0; mi < 4; mi++)
    #pragma unroll
    for (int nb = 0; nb < 4; nb++) acc[mi][nb] = (f4frag){0.f,0.f,0.f,0.f};

  const int soff = (quad ^ ((c16 >> 1) & 3)) * 8;
  int aro[4], bro[4];
  #pragma unroll
  for (int i = 0; i < 4; i++) {
    aro[i] = (wm*64 + i*16 + c16)*32 + soff;
    bro[i] = (wn*64 + i*16 + c16)*32 + soff;
  }

#define QKV_STAGE(KT, BUF) {                                                   \
    const int _k = (KT)*32;                                                    \
    cp16(Xbf + aoff + _k,                 &LA[BUF][lbase]);                    \
    cp16(Xbf + aoff + _k + (size_t)64*CH, &LA[BUF][2048 + lbase]);             \
    cp16(WT  + boff + _k,                 &LB[BUF][lbase]);                    \
    cp16(WT  + boff + _k + (size_t)64*CH, &LB[BUF][2048 + lbase]);             \
    }

  QKV_STAGE(0, 0);
  for (int kt = 0; kt < 32; kt++) {
    const int buf = kt & 1;
    __syncthreads();
    if (kt < 31) { QKV_STAGE(kt+1, buf^1); }
    s8frag a[4], b[4];
    #pragma unroll
    for (int i = 0; i < 4; i++) a[i] = *(const s8frag*)&LA[buf][aro[i]];
    #pragma unroll
    for (int i = 0; i < 4; i++) b[i] = *(const s8frag*)&LB[buf][bro[i]];
    #pragma unroll
    for (int mi = 0; mi < 4; mi++)
      #pragma unroll
      for (int nb = 0; nb < 4; nb++)
        acc[mi][nb] = __builtin_amdgcn_mfma_f32_16x16x32_bf16(a[mi], b[nb], acc[mi][nb], 0, 0, 0);
  }
#undef QKV_STAGE

  const int three = (nt >= 16) ? 2 : (nt >= 8) ? 1 : 0;
  #pragma unroll
  for (int mi = 0; mi < 4; mi++) {
    const int orow = m0 + wm*64 + mi*16 + quad*4;
    if (three == 0) {
      #pragma unroll
      for (int nb = 0; nb < 4; nb++) {
        const int col = n0 + wn*64 + nb*16 + c16;
        const int h = (col >> 6) & 15, d = col & 63;
        ushort_t* qb = Qbf + (size_t)h*NPADQ*64;
        uchar_t*  q8 = Q8 + (size_t)h*NPADQ*64;
        #pragma unroll
        for (int r = 0; r < 4; r++) {
          int row = orow + r;
          float v = (row < TOK) ? acc[mi][nb][r] : 0.f;
          qb[(size_t)row*64 + d] = f2bf(v);
          q8[(size_t)row*64 + d] = f2fp8(v);
        }
      }
    } else if (three == 1) {
      #pragma unroll
      for (int nb = 0; nb < 4; nb++) {
        const int col = n0 + wn*64 + nb*16 + c16;
        const int h = (col >> 6) & 15;
        const int quadK = ((nb & 1) * 2) + (c16 >> 3);
        const int byteoff = (nb >> 1) * 8 + (c16 & 7);
        uchar_t* base = K8 + (size_t)h*NKT*4096;
        #pragma unroll
        for (int r = 0; r < 4; r++) {
          int row = orow + r;
          float v = (row < TOK) ? acc[mi][nb][r] * QSCL : 0.f;
          int tile = row >> 6, b = (row >> 4) & 3, c16K = row & 15;
          base[(size_t)tile*4096 + b*1024 + (quadK*16 + c16K)*16 + byteoff] = f2fp8(v);
        }
      }
    } else {
      const int tile  = orow >> 6;
      const int jj    = orow & 63;
      const int c     = jj >> 5;
      const int t16   = (jj >> 4) & 1;
      const int quadA = (jj >> 2) & 3;
      #pragma unroll
      for (int nb = 0; nb < 4; nb++) {
        const int col = n0 + wn*64 + nb*16 + c16;
        const int h = (col >> 6) & 15, d = col & 63;
        const int dblk = d >> 4, c16A = d & 15;
        ushort_t* base = Vbf + (size_t)h*NKT*4096;
        ushort4 o;
        o.x = f2bf((orow+0 < TOK) ? acc[mi][nb][0] : 0.f);
        o.y = f2bf((orow+1 < TOK) ? acc[mi][nb][1] : 0.f);
        o.z = f2bf((orow+2 < TOK) ? acc[mi][nb][2] : 0.f);
        o.w = f2bf((orow+3 < TOK) ? acc[mi][nb][3] : 0.f);
        *(ushort4*)&base[(size_t)tile*4096 + dblk*1024 + c*512
                         + (quadA*16 + c16A)*8 + 4*t16] = o;
      }
    }
  }
}

// ---------------- sim kernel: thread per (token, head), no wave reductions ----------
// numerator = fp32 x . u_h (exact assoc. rewrite of ghat.q); denom = ||q_bf16||.
__global__ __launch_bounds__(256) void sim_kernel(
    const float* __restrict__ X, const float* __restrict__ U,
    const ushort_t* __restrict__ Qbf, float* __restrict__ sim)
{
  const int gid = blockIdx.x*256 + threadIdx.x;
  const int it = gid >> 4;               // 0..2303
  const int h  = gid & 15;
  const int row = NREG + it;
  const float* xr = X + (size_t)row*CH;
  const float* ur = U + h*CH;
  float num = 0.f;
  for (int k = 0; k < CH; k += 4) {
    float4 xv = *(const float4*)&xr[k];
    float4 uv = *(const float4*)&ur[k];
    num += xv.x*uv.x + xv.y*uv.y + xv.z*uv.z + xv.w*uv.w;
  }
  const ushort_t* qr = Qbf + ((size_t)h*NPADQ + row)*64;
  float n2 = 0.f;
  #pragma unroll
  for (int d = 0; d < 64; d += 4) {
    ushort4 a = *(const ushort4*)&qr[d];
    float q0 = bf2f(a.x), q1 = bf2f(a.y), q2 = bf2f(a.z), q3 = bf2f(a.w);
    n2 += q0*q0 + q1*q1 + q2*q2 + q3*q3;
  }
  float acc = num / sqrtf(n2);
  acc += __shfl_xor(acc, 1, 64);
  acc += __shfl_xor(acc, 2, 64);
  acc += __shfl_xor(acc, 4, 64);
  acc += __shfl_xor(acc, 8, 64);
  if (h == 0) sim[it] = acc * (1.0f/16.0f);
}

// ---------------- mask kernel ------------------------------------------------------
__global__ __launch_bounds__(256) void mask_kernel(
    const float* __restrict__ sim, int* __restrict__ cls,
    float* __restrict__ WP, float* __restrict__ WN)
{
  __shared__ float smn[256], smx[256];
  const int tid = threadIdx.x;
  float mn = 1e30f, mx = -1e30f;
  for (int i = tid; i < NTOK; i += 256) { float s = sim[i]; mn = fminf(mn, s); mx = fmaxf(mx, s); }
  smn[tid] = mn; smx[tid] = mx;
  __syncthreads();
  for (int off = 128; off > 0; off >>= 1) {
    if (tid < off) { smn[tid] = fminf(smn[tid], smn[tid+off]); smx[tid] = fmaxf(smx[tid], smx[tid+off]); }
    __syncthreads();
  }
  mn = smn[0]; mx = smx[0];
  float inv = 1.0f / (mx - mn);
  for (int j = tid; j < NPAD2; j += 256) {
    float wp = 0.f, wn = 0.f; int c = 0;
    if (j < NREG) { wp = 1.f; wn = 1.f; c = 2; }
    else if (j < TOK) {
      bool pos = ((sim[j-NREG] - mn) * inv) > 0.9f;
      c = pos ? 1 : 0;
      wp = pos ? 1.f : 0.f;
      wn = pos ? 0.f : 1.f;
    }
    WP[j] = wp; WN[j] = wn;
    if (j < TOK) cls[j] = c;
  }
}

// ---------------- flash attention: fp8 QK (scale in K8), register-P bf16 PV ---------
__global__ __launch_bounds__(256) void attn_kernel(
    const uchar_t* __restrict__ Q8, const uchar_t* __restrict__ K8,
    const ushort_t* __restrict__ Vbf,
    const float* __restrict__ WP, const float* __restrict__ WN,
    ushort_t* __restrict__ POp, ushort_t* __restrict__ POn,
    float* __restrict__ Lp, float* __restrict__ Ln)
{
  __shared__ __align__(16) uchar_t smem[24576];
  uchar_t* Kst = smem;                 // [2][4096]
  uchar_t* Vst = smem + 8192;          // [2][8192]
  const int tid = threadIdx.x;
  const int w = tid >> 6, lane = tid & 63;
  const int quad = lane >> 4, c16 = lane & 15;
  const int h = blockIdx.y;
  const int half = blockIdx.z;
  const int q0 = blockIdx.x * 64;

  const uchar_t* Qh = Q8 + (size_t)h * NPADQ * 64;
  const uchar_t* gk = K8 + ((size_t)h*NKT + half*HTILES)*4096 + tid*16;
  const uchar_t* gv = (const uchar_t*)Vbf + ((size_t)h*NKT + half*HTILES)*8192 + tid*16;
  const int lw = w * 1024;

  const uchar_t* qp = Qh + (size_t)(q0 + w*16 + c16)*64 + quad*8;
  const long qf0 = *(const long*)(qp);
  const long qf1 = *(const long*)(qp + 32);

  f4frag op[4], on[4];
  #pragma unroll
  for (int nb = 0; nb < 4; nb++) { op[nb] = (f4frag){0.f,0.f,0.f,0.f}; on[nb] = (f4frag){0.f,0.f,0.f,0.f}; }
  float lp = 0.f, ln = 0.f;

  cp16(gk, Kst + lw);
  cp16(gv, Vst + lw);
  cp16(gv + 4096, Vst + 4096 + lw);

  int pb = 0;
  for (int t = 0; t < HTILES; t++) {
    __syncthreads();
    if (t < HTILES-1) {
      cp16(gk + (size_t)(t+1)*4096, Kst + (pb^1)*4096 + lw);
      cp16(gv + (size_t)(t+1)*8192,        Vst + (pb^1)*8192 + lw);
      cp16(gv + (size_t)(t+1)*8192 + 4096, Vst + (pb^1)*8192 + 4096 + lw);
    }
    const int j0 = half*(HTILES*64) + t*64;
    // ---- QK fp8 (K pre-scaled by QSCL) ----
    f4frag st[4];
    #pragma unroll
    for (int b = 0; b < 4; b++) {
      ll2 kv = *(const ll2*)&Kst[pb*4096 + b*1024 + lane*16];
      f4frag z = (f4frag){0.f,0.f,0.f,0.f};
      z     = __builtin_amdgcn_mfma_f32_16x16x32_fp8_fp8(kv.x, qf0, z, 0, 0, 0);
      st[b] = __builtin_amdgcn_mfma_f32_16x16x32_fp8_fp8(kv.y, qf1, z, 0, 0, 0);
    }
    // ---- p = exp2(st); weight; pack into register B-frags (P^T) ----
    unsigned pu[4][2], nu[4][2];
    #pragma unroll
    for (int b = 0; b < 4; b++) {
      float4 wp4 = *(const float4*)&WP[j0 + b*16 + quad*4];
      float4 wn4 = *(const float4*)&WN[j0 + b*16 + quad*4];
      float p0 = __builtin_amdgcn_exp2f(st[b][0]);
      float p1 = __builtin_amdgcn_exp2f(st[b][1]);
      float p2 = __builtin_amdgcn_exp2f(st[b][2]);
      float p3 = __builtin_amdgcn_exp2f(st[b][3]);
      float a0 = p0*wp4.x, a1 = p1*wp4.y, a2 = p2*wp4.z, a3 = p3*wp4.w;
      float b0 = p0*wn4.x, b1 = p1*wn4.y, b2 = p2*wn4.z, b3 = p3*wn4.w;
      lp += (a0+a1)+(a2+a3);
      ln += (b0+b1)+(b2+b3);
      pu[b][0] = pack_bf16(a0, a1); pu[b][1] = pack_bf16(a2, a3);
      nu[b][0] = pack_bf16(b0, b1); nu[b][1] = pack_bf16(b2, b3);
    }
    union Frag { unsigned u[4]; s8frag v; };
    Frag fp0, fp1, fn0, fn1;
    fp0.u[0]=pu[0][0]; fp0.u[1]=pu[0][1]; fp0.u[2]=pu[1][0]; fp0.u[3]=pu[1][1];
    fp1.u[0]=pu[2][0]; fp1.u[1]=pu[2][1]; fp1.u[2]=pu[3][0]; fp1.u[3]=pu[3][1];
    fn0.u[0]=nu[0][0]; fn0.u[1]=nu[0][1]; fn0.u[2]=nu[1][0]; fn0.u[3]=nu[1][1];
    fn1.u[0]=nu[2][0]; fn1.u[1]=nu[2][1]; fn1.u[2]=nu[3][0]; fn1.u[3]=nu[3][1];
    // ---- PV: O^T += V^T-frag (LDS, k-permuted) x P^T-frag (regs) ----
    #pragma unroll
    for (int nb = 0; nb < 4; nb++) {
      s8frag va = *(const s8frag*)&Vst[pb*8192 + nb*2048 + lane*16];
      s8frag vb = *(const s8frag*)&Vst[pb*8192 + nb*2048 + 1024 + lane*16];
      op[nb] = __builtin_amdgcn_mfma_f32_16x16x32_bf16(va, fp0.v, op[nb], 0, 0, 0);
      op[nb] = __builtin_amdgcn_mfma_f32_16x16x32_bf16(vb, fp1.v, op[nb], 0, 0, 0);
      on[nb] = __builtin_amdgcn_mfma_f32_16x16x32_bf16(va, fn0.v, on[nb], 0, 0, 0);
      on[nb] = __builtin_amdgcn_mfma_f32_16x16x32_bf16(vb, fn1.v, on[nb], 0, 0, 0);
    }
    pb ^= 1;
  }

  // ---- epilogue ----
  lp += __shfl_xor(lp, 16, 64); lp += __shfl_xor(lp, 32, 64);
  ln += __shfl_xor(ln, 16, 64); ln += __shfl_xor(ln, 32, 64);
  const int iq = q0 + w*16 + c16;
  if (quad == 0 && iq < TOK) {
    Lp[((size_t)half*NH + h)*NQROW + iq] = lp;
    Ln[((size_t)half*NH + h)*NQROW + iq] = ln;
  }
  if (iq < TOK) {
    const size_t base = (size_t)half*NQROW*CH + (size_t)iq*CH + h*HD;
    #pragma unroll
    for (int nb = 0; nb < 4; nb++) {
      uint2 po, no;
      po.x = pack_bf16(op[nb][0], op[nb][1]);
      po.y = pack_bf16(op[nb][2], op[nb][3]);
      no.x = pack_bf16(on[nb][0], on[nb][1]);
      no.y = pack_bf16(on[nb][2], on[nb][3]);
      *(uint2*)(POp + base + nb*16 + quad*4) = po;
      *(uint2*)(POn + base + nb*16 + quad*4) = no;
    }
  }
}

// ---------------- merge kernel ------------------------------------------------------
__global__ __launch_bounds__(256) void merge_kernel(
    const ushort_t* __restrict__ POp, const ushort_t* __restrict__ POn,
    const float* __restrict__ Lp, const float* __restrict__ Ln,
    const int* __restrict__ cls, ushort_t* __restrict__ AObf)
{
  const int row = blockIdx.x;
  const int c4 = threadIdx.x * 4;
  const int h = c4 >> 6;
  const size_t o0 = (size_t)row*CH + c4;
  const size_t o1 = (size_t)NQROW*CH + o0;
  ushort4 p0 = *(const ushort4*)(POp + o0);
  ushort4 p1 = *(const ushort4*)(POp + o1);
  ushort4 n0 = *(const ushort4*)(POn + o0);
  ushort4 n1 = *(const ushort4*)(POn + o1);
  const float lpt = Lp[(size_t)h*NQROW + row] + Lp[(size_t)(NH+h)*NQROW + row];
  const float lnt = Ln[(size_t)h*NQROW + row] + Ln[(size_t)(NH+h)*NQROW + row];
  const float ilp = 1.f / lpt, iln = 1.f / lnt;
  const int cq = cls[row];
  float vp[4], vn[4], o[4];
  vp[0] = (bf2f(p0.x)+bf2f(p1.x))*ilp; vn[0] = (bf2f(n0.x)+bf2f(n1.x))*iln;
  vp[1] = (bf2f(p0.y)+bf2f(p1.y))*ilp; vn[1] = (bf2f(n0.y)+bf2f(n1.y))*iln;
  vp[2] = (bf2f(p0.z)+bf2f(p1.z))*ilp; vn[2] = (bf2f(n0.z)+bf2f(n1.z))*iln;
  vp[3] = (bf2f(p0.w)+bf2f(p1.w))*ilp; vn[3] = (bf2f(n0.w)+bf2f(n1.w))*iln;
  if (row < NREG) {
    #pragma unroll
    for (int i = 0; i < 4; i++) o[i] = 0.5f*(vp[i]+vn[i]);
  } else if (cq == 1) {
    #pragma unroll
    for (int i = 0; i < 4; i++) o[i] = vp[i];
  } else {
    #pragma unroll
    for (int i = 0; i < 4; i++) o[i] = vn[i];
  }
  uint2 pk;
  pk.x = pack_bf16(o[0], o[1]);
  pk.y = pack_bf16(o[2], o[3]);
  *(uint2*)(AObf + (size_t)row*CH + c4) = pk;
}

// ---------------- Proj GEMM: 128M x 64N tiles (24 KB LDS) ---------------------------
__global__ __launch_bounds__(256) void gemm_proj_mfma(
    const ushort_t* __restrict__ A, const ushort_t* __restrict__ WT,
    const float* __restrict__ bp, float* __restrict__ out)
{
  __shared__ ushort_t LA[2][4096];
  __shared__ ushort_t LB[2][2048];
  const int tid = threadIdx.x;
  const int w = tid >> 6, lane = tid & 63;
  const int quad = lane >> 4, c16 = lane & 15;
  const int wm = w >> 1, wn = w & 1;
  const int nt = blockIdx.x, mt = blockIdx.y;
  const int n0 = nt * 64, m0 = mt * 128;

  const int srow = tid >> 2;
  const int g = (tid & 3) ^ ((tid >> 3) & 3);
  const size_t aoff = (size_t)(m0 + srow)*CH + g*8;
  const size_t boff = (size_t)(n0 + srow)*CH + g*8;
  const int lbase = (tid & 192) * 8;

  f4frag acc[4][2];
  #pragma unroll
  for (int mi = 0; mi < 4; mi++)
    #pragma unroll
    for (int nb = 0; nb < 2; nb++) acc[mi][nb] = (f4frag){0.f,0.f,0.f,0.f};

  const int soff = (quad ^ ((c16 >> 1) & 3)) * 8;
  int aro[4], bro[2];
  #pragma unroll
  for (int i = 0; i < 4; i++) aro[i] = (wm*64 + i*16 + c16)*32 + soff;
  #pragma unroll
  for (int i = 0; i < 2; i++) bro[i] = (wn*32 + i*16 + c16)*32 + soff;

#define PROJ_STAGE(KT, BUF) {                                                  \
    const int _k = (KT)*32;                                                    \
    cp16(A  + aoff + _k,                 &LA[BUF][lbase]);                     \
    cp16(A  + aoff + _k + (size_t)64*CH, &LA[BUF][2048 + lbase]);              \
    cp16(WT + boff + _k,                 &LB[BUF][lbase]);                     \
    }

  PROJ_STAGE(0, 0);
  for (int kt = 0; kt < 32; kt++) {
    const int buf = kt & 1;
    __syncthreads();
    if (kt < 31) { PROJ_STAGE(kt+1, buf^1); }
    s8frag a[4], b[2];
    #pragma unroll
    for (int i = 0; i < 4; i++) a[i] = *(const s8frag*)&LA[buf][aro[i]];
    #pragma unroll
    for (int i = 0; i < 2; i++) b[i] = *(const s8frag*)&LB[buf][bro[i]];
    #pragma unroll
    for (int mi = 0; mi < 4; mi++)
      #pragma unroll
      for (int nb = 0; nb < 2; nb++)
        acc[mi][nb] = __builtin_amdgcn_mfma_f32_16x16x32_bf16(a[mi], b[nb], acc[mi][nb], 0, 0, 0);
  }
#undef PROJ_STAGE

  #pragma unroll
  for (int mi = 0; mi < 4; mi++) {
    const int orow = m0 + wm*64 + mi*16 + quad*4;
    #pragma unroll
    for (int nb = 0; nb < 2; nb++) {
      const int col = n0 + wn*32 + nb*16 + c16;
      const float bias = bp[col];
      #pragma unroll
      for (int r = 0; r < 4; r++) {
        int row = orow + r;
        if (row < TOK) out[(size_t)row*CH + col] = acc[mi][nb][r] + bias;
      }
    }
  }
}

extern "C" void kernel_launch(void* const* d_in, const int* in_sizes, int n_in,
                              void* d_out, int out_size, void* d_ws, size_t ws_size,
                              hipStream_t stream) {
  const float* x      = (const float*)d_in[0];
  const float* g_info = (const float*)d_in[1];
  const float* W_qkv  = (const float*)d_in[2];
  const float* W_proj = (const float*)d_in[3];
  const float* b_proj = (const float*)d_in[4];
  float* out = (float*)d_out;

  float* ws = (float*)d_ws;
  float* SIM = ws;                                   // NTOK
  float* WP  = SIM + NTOK;                           // NPAD2
  float* WN  = WP + NPAD2;                           // NPAD2
  int*   CLS = (int*)(WN + NPAD2);                   // 2312
  float* LpB = (float*)(CLS + 2312);                 // 2*NH*NQROW
  float* LnB = LpB + (size_t)2*NH*NQROW;             // 2*NH*NQROW
  float* U   = LnB + (size_t)2*NH*NQROW;             // NH*CH
  ushort_t* Xbf    = (ushort_t*)(U + (size_t)NH*CH);
  ushort_t* WqkvT  = Xbf    + (size_t)NPADQ*CH;      // 3072*1024
  ushort_t* WprojT = WqkvT  + (size_t)3*CH*CH;       // 1024*1024
  ushort_t* Qbf    = WprojT + (size_t)CH*CH;         // NH*NPADQ*64
  ushort_t* AObf   = Qbf    + (size_t)NH*NPADQ*64;   // NPADQ*CH
  ushort_t* POp    = AObf   + (size_t)NPADQ*CH;      // 2*NQROW*CH
  ushort_t* POn    = POp    + (size_t)2*NQROW*CH;    // 2*NQROW*CH
  uchar_t*  Q8     = (uchar_t*)(POn + (size_t)2*NQROW*CH);  // NH*NPADQ*64
  uchar_t*  K8     = Q8 + (size_t)NH*NPADQ*64;              // NH*NKT*4096 B
  ushort_t* Vbf    = (ushort_t*)(K8 + (size_t)NH*NKT*4096); // NH*NKT*4096 ushorts

  split_x_kernel<<<dim3(NPADQ), 256, 0, stream>>>(x, Xbf);
  pack_w_kernel<<<dim3(64, 16), 256, 0, stream>>>(W_qkv, W_proj, WqkvT, WprojT);
  ghat_kernel<<<dim3(64), 256, 0, stream>>>(g_info, W_qkv, U);
  gemm_qkv_mfma<<<dim3(24, 19), 256, 0, stream>>>(Xbf, WqkvT, Qbf, Q8, K8, Vbf);
  sim_kernel<<<dim3(144), 256, 0, stream>>>(x, U, Qbf, SIM);
  mask_kernel<<<dim3(1), 256, 0, stream>>>(SIM, CLS, WP, WN);
  attn_kernel<<<dim3(37, NH, 2), 256, 0, stream>>>(Q8, K8, Vbf, WP, WN,
                                                   POp, POn, LpB, LnB);
  merge_kernel<<<dim3(TOK), 256, 0, stream>>>(POp, POn, LpB, LnB, CLS, AObf);
  gemm_proj_mfma<<<dim3(16, 19), 256, 0, stream>>>(AObf, WprojT, b_proj, out);
}

// Round 13
// 232.181 us; speedup vs baseline: 1.1412x; 1.1412x over previous
//
#include <hip/hip_runtime.h>
#include <math.h>

#define TOK 2309
#define CH 1024
#define NH 16
#define HD 64
#define NREG 5
#define NTOK (TOK - NREG)    // 2304
#define NPADQ 2432           // 19*128 (query/M padding)
#define NPAD2 2432           // 38*64 key padding == NPADQ (covered by GEMM)
#define NKT 38
#define HTILES 19            // K-tiles per half (attention split-K)
#define NQROW 2368           // 37*64 rows in attention output partials
#define QSCL 0.1803368801f   // 0.125 * log2(e), folded into K8

typedef unsigned short ushort_t;
typedef unsigned char uchar_t;
typedef __attribute__((ext_vector_type(8))) short s8frag;
typedef __attribute__((ext_vector_type(4))) float f4frag;
typedef __attribute__((ext_vector_type(2))) long ll2;

__device__ __forceinline__ unsigned short f2bf(float x){
  union { float f; unsigned u; } v; v.f = x;
  unsigned r = v.u + 0x7FFF + ((v.u >> 16) & 1);
  return (unsigned short)(r >> 16);
}
__device__ __forceinline__ float bf2f(unsigned short u){
  union { unsigned u32; float f; } v; v.u32 = ((unsigned)u) << 16;
  return v.f;
}
__device__ __forceinline__ unsigned pack_bf16(float lo, float hi){
  union { float f; unsigned u; } a, b;
  a.f = lo; b.f = hi;
  return __builtin_amdgcn_perm(b.u + 0x8000u, a.u + 0x8000u, 0x07060302u);
}
__device__ __forceinline__ uchar_t f2fp8(float x){
  return (uchar_t)(__builtin_amdgcn_cvt_pk_fp8_f32(x, x, 0, false) & 0xff);
}
// async global->LDS 16B/lane; lds ptr must be wave-uniform (HW adds lane*16)
__device__ __forceinline__ void cp16(const void* g, void* l){
  __builtin_amdgcn_global_load_lds(
      (const __attribute__((address_space(1))) unsigned int*)g,
      (__attribute__((address_space(3))) unsigned int*)l, 16, 0, 0);
}

// ---------------- prep: split_x + pack_w + ghat fused (independent block ranges) ----
__global__ __launch_bounds__(256) void prep_kernel(
    const float* __restrict__ X, const float* __restrict__ Wqkv,
    const float* __restrict__ Wproj, const float* __restrict__ G,
    ushort_t* __restrict__ Xbf, ushort_t* __restrict__ WqkvT,
    ushort_t* __restrict__ WprojT, float* __restrict__ UT)
{
  const int tid = threadIdx.x;
  int bx = blockIdx.x;
  if (bx < NPADQ) {
    // ---- X -> bf16 row (pad rows zero) ----
    const int row = bx;
    const int c4 = tid * 4;
    ushort4 h4 = {0,0,0,0};
    if (row < TOK) {
      float4 v = *(const float4*)&X[(size_t)row*CH + c4];
      h4.x = f2bf(v.x); h4.y = f2bf(v.y); h4.z = f2bf(v.z); h4.w = f2bf(v.w);
    }
    *(ushort4*)&Xbf[(size_t)row*CH + c4] = h4;
    return;
  }
  bx -= NPADQ;
  if (bx < 1024) {
    // ---- transpose W: W(1024 x N) -> WT(N x 1024) bf16 ----
    __shared__ float T[64][68];
    int nb_i = bx & 63;
    const int k0 = (bx >> 6) * 64;
    const float* W; ushort_t* WT; int N;
    if (nb_i < 48) { W = Wqkv; WT = WqkvT; N = 3*CH; }
    else           { W = Wproj; WT = WprojT; N = CH; nb_i -= 48; }
    const int n0 = nb_i * 64;
    const int lr = tid >> 4;
    const int lc = (tid & 15) * 4;
    #pragma unroll
    for (int s = 0; s < 4; s++) {
      float4 v = *(const float4*)&W[(size_t)(k0 + lr + s*16) * N + n0 + lc];
      *(float4*)&T[lr + s*16][lc] = v;
    }
    __syncthreads();
    const int nl = tid >> 2;
    const int kc = (tid & 3) * 16;
    ushort_t* dh = WT + (size_t)(n0 + nl) * CH + k0 + kc;
    #pragma unroll
    for (int g = 0; g < 4; g++) {
      ushort4 oh;
      oh.x = f2bf(T[kc+g*4+0][nl]); oh.y = f2bf(T[kc+g*4+1][nl]);
      oh.z = f2bf(T[kc+g*4+2][nl]); oh.w = f2bf(T[kc+g*4+3][nl]);
      *(ushort4*)&dh[g*4] = oh;
    }
    return;
  }
  bx -= 1024;
  {
    // ---- UT[k][h] = W_q[:,h*64..] . ghat_h ----
    const int k = bx * 16 + (tid >> 4);
    const int h = tid & 15;
    const float* g = G + h*64;
    float n2 = 0.f;
    #pragma unroll
    for (int d = 0; d < 64; d += 4) {
      float4 gv = *(const float4*)&g[d];
      n2 += gv.x*gv.x + gv.y*gv.y + gv.z*gv.z + gv.w*gv.w;
    }
    const float inv = 1.f / sqrtf(n2);
    const float* wr = Wqkv + (size_t)k*(3*CH) + h*64;
    float dot = 0.f;
    #pragma unroll
    for (int d = 0; d < 64; d += 4) {
      float4 wv = *(const float4*)&wr[d];
      float4 gv = *(const float4*)&g[d];
      dot += wv.x*gv.x + wv.y*gv.y + wv.z*gv.z + wv.w*gv.w;
    }
    UT[k*16 + h] = dot * inv;
  }
}

// ---------------- QKV GEMM: uniform 128x128 tile, single-plane bf16 -----------------
__global__ __launch_bounds__(256) void gemm_qkv_mfma(
    const ushort_t* __restrict__ Xbf, const ushort_t* __restrict__ WT,
    ushort_t* __restrict__ Qbf, uchar_t* __restrict__ Q8,
    uchar_t* __restrict__ K8, ushort_t* __restrict__ Vbf)
{
  __shared__ ushort_t LA[2][4096];
  __shared__ ushort_t LB[2][4096];
  const int tid = threadIdx.x;
  const int w = tid >> 6, lane = tid & 63;
  const int quad = lane >> 4, c16 = lane & 15;
  const int wm = w >> 1, wn = w & 1;
  const int nt = blockIdx.x, mt = blockIdx.y;
  const int n0 = nt * 128, m0 = mt * 128;

  const int srow = tid >> 2;
  const int g = (tid & 3) ^ ((tid >> 3) & 3);
  const size_t aoff = (size_t)(m0 + srow)*CH + g*8;
  const size_t boff = (size_t)(n0 + srow)*CH + g*8;
  const int lbase = (tid & 192) * 8;

  f4frag acc[4][4];
  #pragma unroll
  for (int mi = 0; mi < 4; mi++)
    #pragma unroll
    for (int nb = 0; nb < 4; nb++) acc[mi][nb] = (f4frag){0.f,0.f,0.f,0.f};

  const int soff = (quad ^ ((c16 >> 1) & 3)) * 8;
  int aro[4], bro[4];
  #pragma unroll
  for (int i = 0; i < 4; i++) {
    aro[i] = (wm*64 + i*16 + c16)*32 + soff;
    bro[i] = (wn*64 + i*16 + c16)*32 + soff;
  }

#define QKV_STAGE(KT, BUF) {                                                   \
    const int _k = (KT)*32;                                                    \
    cp16(Xbf + aoff + _k,                 &LA[BUF][lbase]);                    \
    cp16(Xbf + aoff + _k + (size_t)64*CH, &LA[BUF][2048 + lbase]);             \
    cp16(WT  + boff + _k,                 &LB[BUF][lbase]);                    \
    cp16(WT  + boff + _k + (size_t)64*CH, &LB[BUF][2048 + lbase]);             \
    }

  QKV_STAGE(0, 0);
  for (int kt = 0; kt < 32; kt++) {
    const int buf = kt & 1;
    __syncthreads();
    if (kt < 31) { QKV_STAGE(kt+1, buf^1); }
    s8frag a[4], b[4];
    #pragma unroll
    for (int i = 0; i < 4; i++) a[i] = *(const s8frag*)&LA[buf][aro[i]];
    #pragma unroll
    for (int i = 0; i < 4; i++) b[i] = *(const s8frag*)&LB[buf][bro[i]];
    #pragma unroll
    for (int mi = 0; mi < 4; mi++)
      #pragma unroll
      for (int nb = 0; nb < 4; nb++)
        acc[mi][nb] = __builtin_amdgcn_mfma_f32_16x16x32_bf16(a[mi], b[nb], acc[mi][nb], 0, 0, 0);
  }
#undef QKV_STAGE

  const int three = (nt >= 16) ? 2 : (nt >= 8) ? 1 : 0;
  #pragma unroll
  for (int mi = 0; mi < 4; mi++) {
    const int orow = m0 + wm*64 + mi*16 + quad*4;
    if (three == 0) {
      #pragma unroll
      for (int nb = 0; nb < 4; nb++) {
        const int col = n0 + wn*64 + nb*16 + c16;
        const int h = (col >> 6) & 15, d = col & 63;
        ushort_t* qb = Qbf + (size_t)h*NPADQ*64;
        uchar_t*  q8 = Q8 + (size_t)h*NPADQ*64;
        #pragma unroll
        for (int r = 0; r < 4; r++) {
          int row = orow + r;
          float v = (row < TOK) ? acc[mi][nb][r] : 0.f;
          qb[(size_t)row*64 + d] = f2bf(v);
          q8[(size_t)row*64 + d] = f2fp8(v);
        }
      }
    } else if (three == 1) {
      #pragma unroll
      for (int nb = 0; nb < 4; nb++) {
        const int col = n0 + wn*64 + nb*16 + c16;
        const int h = (col >> 6) & 15;
        const int quadK = ((nb & 1) * 2) + (c16 >> 3);
        const int byteoff = (nb >> 1) * 8 + (c16 & 7);
        uchar_t* base = K8 + (size_t)h*NKT*4096;
        #pragma unroll
        for (int r = 0; r < 4; r++) {
          int row = orow + r;
          float v = (row < TOK) ? acc[mi][nb][r] * QSCL : 0.f;
          int tile = row >> 6, b = (row >> 4) & 3, c16K = row & 15;
          base[(size_t)tile*4096 + b*1024 + (quadK*16 + c16K)*16 + byteoff] = f2fp8(v);
        }
      }
    } else {
      const int tile  = orow >> 6;
      const int jj    = orow & 63;
      const int c     = jj >> 5;
      const int t16   = (jj >> 4) & 1;
      const int quadA = (jj >> 2) & 3;
      #pragma unroll
      for (int nb = 0; nb < 4; nb++) {
        const int col = n0 + wn*64 + nb*16 + c16;
        const int h = (col >> 6) & 15, d = col & 63;
        const int dblk = d >> 4, c16A = d & 15;
        ushort_t* base = Vbf + (size_t)h*NKT*4096;
        ushort4 o;
        o.x = f2bf((orow+0 < TOK) ? acc[mi][nb][0] : 0.f);
        o.y = f2bf((orow+1 < TOK) ? acc[mi][nb][1] : 0.f);
        o.z = f2bf((orow+2 < TOK) ? acc[mi][nb][2] : 0.f);
        o.w = f2bf((orow+3 < TOK) ? acc[mi][nb][3] : 0.f);
        *(ushort4*)&base[(size_t)tile*4096 + dblk*1024 + c*512
                         + (quadA*16 + c16A)*8 + 4*t16] = o;
      }
    }
  }
}

// ---------------- sim kernel: block per token, LDS x-row, coalesced UT --------------
__global__ __launch_bounds__(256) void sim_kernel(
    const float* __restrict__ X, const float* __restrict__ UT,
    const ushort_t* __restrict__ Qbf, float* __restrict__ sim)
{
  __shared__ float xs[1024];
  __shared__ float pnum[16][17];
  __shared__ float pn2[16][17];
  const int tid = threadIdx.x;
  const int row = NREG + blockIdx.x;
  *(float4*)&xs[tid*4] = *(const float4*)&X[(size_t)row*CH + tid*4];
  __syncthreads();
  const int h = tid & 15, seg = tid >> 4;
  const int k0 = seg * 64;
  float num = 0.f;
  #pragma unroll
  for (int j = 0; j < 64; j++)
    num += xs[k0 + j] * UT[(k0 + j)*16 + h];
  const ushort_t* qr = Qbf + ((size_t)h*NPADQ + row)*64 + seg*4;
  ushort4 a = *(const ushort4*)qr;
  float q0 = bf2f(a.x), q1 = bf2f(a.y), q2 = bf2f(a.z), q3 = bf2f(a.w);
  pnum[seg][h] = num;
  pn2[seg][h] = q0*q0 + q1*q1 + q2*q2 + q3*q3;
  __syncthreads();
  if (tid < 16) {
    float nsum = 0.f, dsum = 0.f;
    #pragma unroll
    for (int s = 0; s < 16; s++) { nsum += pnum[s][tid]; dsum += pn2[s][tid]; }
    float acc = nsum / sqrtf(dsum);
    acc += __shfl_xor(acc, 1, 64);
    acc += __shfl_xor(acc, 2, 64);
    acc += __shfl_xor(acc, 4, 64);
    acc += __shfl_xor(acc, 8, 64);
    if (tid == 0) sim[blockIdx.x] = acc * (1.0f/16.0f);
  }
}

// ---------------- mask kernel ------------------------------------------------------
__global__ __launch_bounds__(256) void mask_kernel(
    const float* __restrict__ sim, int* __restrict__ cls,
    float* __restrict__ WP, float* __restrict__ WN)
{
  __shared__ float smn[256], smx[256];
  const int tid = threadIdx.x;
  float mn = 1e30f, mx = -1e30f;
  for (int i = tid; i < NTOK; i += 256) { float s = sim[i]; mn = fminf(mn, s); mx = fmaxf(mx, s); }
  smn[tid] = mn; smx[tid] = mx;
  __syncthreads();
  for (int off = 128; off > 0; off >>= 1) {
    if (tid < off) { smn[tid] = fminf(smn[tid], smn[tid+off]); smx[tid] = fmaxf(smx[tid], smx[tid+off]); }
    __syncthreads();
  }
  mn = smn[0]; mx = smx[0];
  float inv = 1.0f / (mx - mn);
  for (int j = tid; j < NPAD2; j += 256) {
    float wp = 0.f, wn = 0.f; int c = 0;
    if (j < NREG) { wp = 1.f; wn = 1.f; c = 2; }
    else if (j < TOK) {
      bool pos = ((sim[j-NREG] - mn) * inv) > 0.9f;
      c = pos ? 1 : 0;
      wp = pos ? 1.f : 0.f;
      wn = pos ? 0.f : 1.f;
    }
    WP[j] = wp; WN[j] = wn;
    if (j < TOK) cls[j] = c;
  }
}

// ---------------- flash attention: fp8 QK (scale in K8), register-P bf16 PV ---------
__global__ __launch_bounds__(256) void attn_kernel(
    const uchar_t* __restrict__ Q8, const uchar_t* __restrict__ K8,
    const ushort_t* __restrict__ Vbf,
    const float* __restrict__ WP, const float* __restrict__ WN,
    ushort_t* __restrict__ POp, ushort_t* __restrict__ POn,
    float* __restrict__ Lp, float* __restrict__ Ln)
{
  __shared__ __align__(16) uchar_t smem[24576];
  uchar_t* Kst = smem;                 // [2][4096]
  uchar_t* Vst = smem + 8192;          // [2][8192]
  const int tid = threadIdx.x;
  const int w = tid >> 6, lane = tid & 63;
  const int quad = lane >> 4, c16 = lane & 15;
  const int h = blockIdx.y;
  const int half = blockIdx.z;
  const int q0 = blockIdx.x * 64;

  const uchar_t* Qh = Q8 + (size_t)h * NPADQ * 64;
  const uchar_t* gk = K8 + ((size_t)h*NKT + half*HTILES)*4096 + tid*16;
  const uchar_t* gv = (const uchar_t*)Vbf + ((size_t)h*NKT + half*HTILES)*8192 + tid*16;
  const int lw = w * 1024;

  const uchar_t* qp = Qh + (size_t)(q0 + w*16 + c16)*64 + quad*8;
  const long qf0 = *(const long*)(qp);
  const long qf1 = *(const long*)(qp + 32);

  f4frag op[4], on[4];
  #pragma unroll
  for (int nb = 0; nb < 4; nb++) { op[nb] = (f4frag){0.f,0.f,0.f,0.f}; on[nb] = (f4frag){0.f,0.f,0.f,0.f}; }
  float lp = 0.f, ln = 0.f;

  cp16(gk, Kst + lw);
  cp16(gv, Vst + lw);
  cp16(gv + 4096, Vst + 4096 + lw);

  int pb = 0;
  for (int t = 0; t < HTILES; t++) {
    __syncthreads();
    if (t < HTILES-1) {
      cp16(gk + (size_t)(t+1)*4096, Kst + (pb^1)*4096 + lw);
      cp16(gv + (size_t)(t+1)*8192,        Vst + (pb^1)*8192 + lw);
      cp16(gv + (size_t)(t+1)*8192 + 4096, Vst + (pb^1)*8192 + 4096 + lw);
    }
    const int j0 = half*(HTILES*64) + t*64;
    f4frag st[4];
    #pragma unroll
    for (int b = 0; b < 4; b++) {
      ll2 kv = *(const ll2*)&Kst[pb*4096 + b*1024 + lane*16];
      f4frag z = (f4frag){0.f,0.f,0.f,0.f};
      z     = __builtin_amdgcn_mfma_f32_16x16x32_fp8_fp8(kv.x, qf0, z, 0, 0, 0);
      st[b] = __builtin_amdgcn_mfma_f32_16x16x32_fp8_fp8(kv.y, qf1, z, 0, 0, 0);
    }
    unsigned pu[4][2], nu[4][2];
    #pragma unroll
    for (int b = 0; b < 4; b++) {
      float4 wp4 = *(const float4*)&WP[j0 + b*16 + quad*4];
      float4 wn4 = *(const float4*)&WN[j0 + b*16 + quad*4];
      float p0 = __builtin_amdgcn_exp2f(st[b][0]);
      float p1 = __builtin_amdgcn_exp2f(st[b][1]);
      float p2 = __builtin_amdgcn_exp2f(st[b][2]);
      float p3 = __builtin_amdgcn_exp2f(st[b][3]);
      float a0 = p0*wp4.x, a1 = p1*wp4.y, a2 = p2*wp4.z, a3 = p3*wp4.w;
      float b0 = p0*wn4.x, b1 = p1*wn4.y, b2 = p2*wn4.z, b3 = p3*wn4.w;
      lp += (a0+a1)+(a2+a3);
      ln += (b0+b1)+(b2+b3);
      pu[b][0] = pack_bf16(a0, a1); pu[b][1] = pack_bf16(a2, a3);
      nu[b][0] = pack_bf16(b0, b1); nu[b][1] = pack_bf16(b2, b3);
    }
    union Frag { unsigned u[4]; s8frag v; };
    Frag fp0, fp1, fn0, fn1;
    fp0.u[0]=pu[0][0]; fp0.u[1]=pu[0][1]; fp0.u[2]=pu[1][0]; fp0.u[3]=pu[1][1];
    fp1.u[0]=pu[2][0]; fp1.u[1]=pu[2][1]; fp1.u[2]=pu[3][0]; fp1.u[3]=pu[3][1];
    fn0.u[0]=nu[0][0]; fn0.u[1]=nu[0][1]; fn0.u[2]=nu[1][0]; fn0.u[3]=nu[1][1];
    fn1.u[0]=nu[2][0]; fn1.u[1]=nu[2][1]; fn1.u[2]=nu[3][0]; fn1.u[3]=nu[3][1];
    #pragma unroll
    for (int nb = 0; nb < 4; nb++) {
      s8frag va = *(const s8frag*)&Vst[pb*8192 + nb*2048 + lane*16];
      s8frag vb = *(const s8frag*)&Vst[pb*8192 + nb*2048 + 1024 + lane*16];
      op[nb] = __builtin_amdgcn_mfma_f32_16x16x32_bf16(va, fp0.v, op[nb], 0, 0, 0);
      op[nb] = __builtin_amdgcn_mfma_f32_16x16x32_bf16(vb, fp1.v, op[nb], 0, 0, 0);
      on[nb] = __builtin_amdgcn_mfma_f32_16x16x32_bf16(va, fn0.v, on[nb], 0, 0, 0);
      on[nb] = __builtin_amdgcn_mfma_f32_16x16x32_bf16(vb, fn1.v, on[nb], 0, 0, 0);
    }
    pb ^= 1;
  }

  lp += __shfl_xor(lp, 16, 64); lp += __shfl_xor(lp, 32, 64);
  ln += __shfl_xor(ln, 16, 64); ln += __shfl_xor(ln, 32, 64);
  const int iq = q0 + w*16 + c16;
  if (quad == 0 && iq < TOK) {
    Lp[((size_t)half*NH + h)*NQROW + iq] = lp;
    Ln[((size_t)half*NH + h)*NQROW + iq] = ln;
  }
  if (iq < TOK) {
    const size_t base = (size_t)half*NQROW*CH + (size_t)iq*CH + h*HD;
    #pragma unroll
    for (int nb = 0; nb < 4; nb++) {
      uint2 po, no;
      po.x = pack_bf16(op[nb][0], op[nb][1]);
      po.y = pack_bf16(op[nb][2], op[nb][3]);
      no.x = pack_bf16(on[nb][0], on[nb][1]);
      no.y = pack_bf16(on[nb][2], on[nb][3]);
      *(uint2*)(POp + base + nb*16 + quad*4) = po;
      *(uint2*)(POn + base + nb*16 + quad*4) = no;
    }
  }
}

// ---------------- merge kernel ------------------------------------------------------
__global__ __launch_bounds__(256) void merge_kernel(
    const ushort_t* __restrict__ POp, const ushort_t* __restrict__ POn,
    const float* __restrict__ Lp, const float* __restrict__ Ln,
    const int* __restrict__ cls, ushort_t* __restrict__ AObf)
{
  const int row = blockIdx.x;
  const int c4 = threadIdx.x * 4;
  const int h = c4 >> 6;
  const size_t o0 = (size_t)row*CH + c4;
  const size_t o1 = (size_t)NQROW*CH + o0;
  ushort4 p0 = *(const ushort4*)(POp + o0);
  ushort4 p1 = *(const ushort4*)(POp + o1);
  ushort4 n0 = *(const ushort4*)(POn + o0);
  ushort4 n1 = *(const ushort4*)(POn + o1);
  const float lpt = Lp[(size_t)h*NQROW + row] + Lp[(size_t)(NH+h)*NQROW + row];
  const float lnt = Ln[(size_t)h*NQROW + row] + Ln[(size_t)(NH+h)*NQROW + row];
  const float ilp = 1.f / lpt, iln = 1.f / lnt;
  const int cq = cls[row];
  float vp[4], vn[4], o[4];
  vp[0] = (bf2f(p0.x)+bf2f(p1.x))*ilp; vn[0] = (bf2f(n0.x)+bf2f(n1.x))*iln;
  vp[1] = (bf2f(p0.y)+bf2f(p1.y))*ilp; vn[1] = (bf2f(n0.y)+bf2f(n1.y))*iln;
  vp[2] = (bf2f(p0.z)+bf2f(p1.z))*ilp; vn[2] = (bf2f(n0.z)+bf2f(n1.z))*iln;
  vp[3] = (bf2f(p0.w)+bf2f(p1.w))*ilp; vn[3] = (bf2f(n0.w)+bf2f(n1.w))*iln;
  if (row < NREG) {
    #pragma unroll
    for (int i = 0; i < 4; i++) o[i] = 0.5f*(vp[i]+vn[i]);
  } else if (cq == 1) {
    #pragma unroll
    for (int i = 0; i < 4; i++) o[i] = vp[i];
  } else {
    #pragma unroll
    for (int i = 0; i < 4; i++) o[i] = vn[i];
  }
  uint2 pk;
  pk.x = pack_bf16(o[0], o[1]);
  pk.y = pack_bf16(o[2], o[3]);
  *(uint2*)(AObf + (size_t)row*CH + c4) = pk;
}

// ---------------- Proj GEMM: 128M x 64N tiles (24 KB LDS) ---------------------------
__global__ __launch_bounds__(256) void gemm_proj_mfma(
    const ushort_t* __restrict__ A, const ushort_t* __restrict__ WT,
    const float* __restrict__ bp, float* __restrict__ out)
{
  __shared__ ushort_t LA[2][4096];
  __shared__ ushort_t LB[2][2048];
  const int tid = threadIdx.x;
  const int w = tid >> 6, lane = tid & 63;
  const int quad = lane >> 4, c16 = lane & 15;
  const int wm = w >> 1, wn = w & 1;
  const int nt = blockIdx.x, mt = blockIdx.y;
  const int n0 = nt * 64, m0 = mt * 128;

  const int srow = tid >> 2;
  const int g = (tid & 3) ^ ((tid >> 3) & 3);
  const size_t aoff = (size_t)(m0 + srow)*CH + g*8;
  const size_t boff = (size_t)(n0 + srow)*CH + g*8;
  const int lbase = (tid & 192) * 8;

  f4frag acc[4][2];
  #pragma unroll
  for (int mi = 0; mi < 4; mi++)
    #pragma unroll
    for (int nb = 0; nb < 2; nb++) acc[mi][nb] = (f4frag){0.f,0.f,0.f,0.f};

  const int soff = (quad ^ ((c16 >> 1) & 3)) * 8;
  int aro[4], bro[2];
  #pragma unroll
  for (int i = 0; i < 4; i++) aro[i] = (wm*64 + i*16 + c16)*32 + soff;
  #pragma unroll
  for (int i = 0; i < 2; i++) bro[i] = (wn*32 + i*16 + c16)*32 + soff;

#define PROJ_STAGE(KT, BUF) {                                                  \
    const int _k = (KT)*32;                                                    \
    cp16(A  + aoff + _k,                 &LA[BUF][lbase]);                     \
    cp16(A  + aoff + _k + (size_t)64*CH, &LA[BUF][2048 + lbase]);              \
    cp16(WT + boff + _k,                 &LB[BUF][lbase]);                     \
    }

  PROJ_STAGE(0, 0);
  for (int kt = 0; kt < 32; kt++) {
    const int buf = kt & 1;
    __syncthreads();
    if (kt < 31) { PROJ_STAGE(kt+1, buf^1); }
    s8frag a[4], b[2];
    #pragma unroll
    for (int i = 0; i < 4; i++) a[i] = *(const s8frag*)&LA[buf][aro[i]];
    #pragma unroll
    for (int i = 0; i < 2; i++) b[i] = *(const s8frag*)&LB[buf][bro[i]];
    #pragma unroll
    for (int mi = 0; mi < 4; mi++)
      #pragma unroll
      for (int nb = 0; nb < 2; nb++)
        acc[mi][nb] = __builtin_amdgcn_mfma_f32_16x16x32_bf16(a[mi], b[nb], acc[mi][nb], 0, 0, 0);
  }
#undef PROJ_STAGE

  #pragma unroll
  for (int mi = 0; mi < 4; mi++) {
    const int orow = m0 + wm*64 + mi*16 + quad*4;
    #pragma unroll
    for (int nb = 0; nb < 2; nb++) {
      const int col = n0 + wn*32 + nb*16 + c16;
      const float bias = bp[col];
      #pragma unroll
      for (int r = 0; r < 4; r++) {
        int row = orow + r;
        if (row < TOK) out[(size_t)row*CH + col] = acc[mi][nb][r] + bias;
      }
    }
  }
}

extern "C" void kernel_launch(void* const* d_in, const int* in_sizes, int n_in,
                              void* d_out, int out_size, void* d_ws, size_t ws_size,
                              hipStream_t stream) {
  const float* x      = (const float*)d_in[0];
  const float* g_info = (const float*)d_in[1];
  const float* W_qkv  = (const float*)d_in[2];
  const float* W_proj = (const float*)d_in[3];
  const float* b_proj = (const float*)d_in[4];
  float* out = (float*)d_out;

  float* ws = (float*)d_ws;
  float* SIM = ws;                                   // NTOK
  float* WP  = SIM + NTOK;                           // NPAD2
  float* WN  = WP + NPAD2;                           // NPAD2
  int*   CLS = (int*)(WN + NPAD2);                   // 2312
  float* LpB = (float*)(CLS + 2312);                 // 2*NH*NQROW
  float* LnB = LpB + (size_t)2*NH*NQROW;             // 2*NH*NQROW
  float* UT  = LnB + (size_t)2*NH*NQROW;             // CH*NH
  ushort_t* Xbf    = (ushort_t*)(UT + (size_t)CH*NH);
  ushort_t* WqkvT  = Xbf    + (size_t)NPADQ*CH;      // 3072*1024
  ushort_t* WprojT = WqkvT  + (size_t)3*CH*CH;       // 1024*1024
  ushort_t* Qbf    = WprojT + (size_t)CH*CH;         // NH*NPADQ*64
  ushort_t* AObf   = Qbf    + (size_t)NH*NPADQ*64;   // NPADQ*CH
  ushort_t* POp    = AObf   + (size_t)NPADQ*CH;      // 2*NQROW*CH
  ushort_t* POn    = POp    + (size_t)2*NQROW*CH;    // 2*NQROW*CH
  uchar_t*  Q8     = (uchar_t*)(POn + (size_t)2*NQROW*CH);  // NH*NPADQ*64
  uchar_t*  K8     = Q8 + (size_t)NH*NPADQ*64;              // NH*NKT*4096 B
  ushort_t* Vbf    = (ushort_t*)(K8 + (size_t)NH*NKT*4096); // NH*NKT*4096 ushorts

  prep_kernel<<<dim3(NPADQ + 1024 + 64), 256, 0, stream>>>(
      x, W_qkv, W_proj, g_info, Xbf, WqkvT, WprojT, UT);
  gemm_qkv_mfma<<<dim3(24, 19), 256, 0, stream>>>(Xbf, WqkvT, Qbf, Q8, K8, Vbf);
  sim_kernel<<<dim3(NTOK), 256, 0, stream>>>(x, UT, Qbf, SIM);
  mask_kernel<<<dim3(1), 256, 0, stream>>>(SIM, CLS, WP, WN);
  attn_kernel<<<dim3(37, NH, 2), 256, 0, stream>>>(Q8, K8, Vbf, WP, WN,
                                                   POp, POn, LpB, LnB);
  merge_kernel<<<dim3(TOK), 256, 0, stream>>>(POp, POn, LpB, LnB, CLS, AObf);
  gemm_proj_mfma<<<dim3(16, 19), 256, 0, stream>>>(AObf, WprojT, b_proj, out);
}